// Round 4
// baseline (277.558 us; speedup 1.0000x reference)
//
#include <hip/hip_runtime.h>

#define TPB 256

namespace {
constexpr int B = 8, F = 6, NB = 5, NS = 7, H = 192, W = 192, C = 3;
constexpr int FM1 = F - 1;                 // frames 1..5
constexpr int HW = H * W;                  // 36864
constexpr int HW4 = HW / 4;                // 9216 float4 per plane
constexpr int PAIRS = B * FM1;             // 40
constexpr int BPP = HW4 / TPB;             // 36 blocks per pair
constexpr float EPS = 1e-7f;
constexpr float LN2 = 0.69314718055994530942f;
constexpr float K_BCE = LN2 / (float)HW;
constexpr float COEF = 0.1f / (float)C;
}

__device__ __forceinline__ void fma4(float4& acc, float s, const float4& v) {
  acc.x = fmaf(s, v.x, acc.x); acc.y = fmaf(s, v.y, acc.y);
  acc.z = fmaf(s, v.z, acc.z); acc.w = fmaf(s, v.w, acc.w);
}
__device__ __forceinline__ float clampp(float p) {
  return __builtin_amdgcn_fmed3f(p, EPS, 1.0f - EPS);  // v_med3_f32
}

// ---- K1: masks/vis (83 MB, 1 useful bit each) -> 14-bit code per pixel ----
__global__ __launch_bounds__(TPB) void pack_bits(
    const float* __restrict__ masks,  // [B,F,NS,H,W]
    const float* __restrict__ vis,    // [B,F,NS,H,W]
    ushort* __restrict__ bm)          // [PAIRS, HW] codes
{
  const int blk = blockIdx.x;
  const int pair = blk / BPP;
  const int chunk = blk - pair * BPP;
  const int b = pair / FM1;
  const int f = pair - b * FM1 + 1;
  const int bf = b * F + f;

  const float4* mp = (const float4*)(masks + (size_t)bf * NS * HW);
  const float4* vp = (const float4*)(vis   + (size_t)bf * NS * HW);
  const int q = chunk * TPB + threadIdx.x;

  float4 m4[NS], v4[NS];
  #pragma unroll
  for (int s = 0; s < NS; ++s) m4[s] = mp[s * HW4 + q];
  #pragma unroll
  for (int s = 0; s < NS; ++s) v4[s] = vp[s * HW4 + q];

  unsigned cx = 0, cy = 0, cz = 0, cw = 0;
  #pragma unroll
  for (int s = 0; s < NS; ++s) {
    cx |= ((m4[s].x > 0.5f) ? 1u : 0u) << s;
    cy |= ((m4[s].y > 0.5f) ? 1u : 0u) << s;
    cz |= ((m4[s].z > 0.5f) ? 1u : 0u) << s;
    cw |= ((m4[s].w > 0.5f) ? 1u : 0u) << s;
    cx |= ((v4[s].x > 0.5f) ? 1u : 0u) << (NS + s);
    cy |= ((v4[s].y > 0.5f) ? 1u : 0u) << (NS + s);
    cz |= ((v4[s].z > 0.5f) ? 1u : 0u) << (NS + s);
    cw |= ((v4[s].w > 0.5f) ? 1u : 0u) << (NS + s);
  }
  ushort4 o;
  o.x = (ushort)cx; o.y = (ushort)cy; o.z = (ushort)cz; o.w = (ushort)cw;
  ((ushort4*)bm)[(size_t)pair * HW4 + q] = o;  // 8B/lane coalesced store
}

// ---- K2: seg + recon + tgt + codes (139 MB, 24 streams/wave) ----
__global__ __launch_bounds__(TPB, 5) void em_rec_loss_kernel(
    const float* __restrict__ seg,    // [B,F,NB,H,W]
    const float* __restrict__ recon,  // [B,F,NB,C,H,W]
    const float* __restrict__ rtgt,   // [B,F,C,H,W]
    const ushort* __restrict__ bm,    // [PAIRS, HW]
    const float* __restrict__ attn,   // [B,F,NS,NB]
    float* __restrict__ out)
{
  const int blk = blockIdx.x;
  const int pair = blk / BPP;
  const int chunk = blk - pair * BPP;
  const int b = pair / FM1;
  const int f = pair - b * FM1 + 1;
  const int bf = b * F + f;

  // block-uniform pre-scaled attn weights
  float aw[NS][NB], av[NS][NB];
  const float* at = attn + (size_t)bf * NS * NB;
  #pragma unroll
  for (int s = 0; s < NS; ++s)
    #pragma unroll
    for (int n = 0; n < NB; ++n) {
      const float a = at[s * NB + n];
      aw[s][n] = a * K_BCE;
      av[s][n] = a * COEF;
    }
  float AK[NB];
  #pragma unroll
  for (int n = 0; n < NB; ++n) {
    float t = 0.f;
    #pragma unroll
    for (int s = 0; s < NS; ++s) t += aw[s][n];
    AK[n] = t;
  }

  const float4* sp = (const float4*)(seg   + (size_t)bf * NB * HW);
  const float4* rp = (const float4*)(recon + (size_t)bf * NB * C * HW);
  const float4* tp = (const float4*)(rtgt  + (size_t)bf * C * HW);
  const int q = chunk * TPB + threadIdx.x;

  // independent loads up front
  const ushort4 code = ((const ushort4*)bm)[(size_t)pair * HW4 + q];
  float4 tg[C];
  #pragma unroll
  for (int c = 0; c < C; ++c) tg[c] = tp[c * HW4 + q];
  float4 p4[NB];
  #pragma unroll
  for (int n = 0; n < NB; ++n) p4[n] = sp[n * HW4 + q];

  // reconstruct wt/wv from the bit code (VALU is idle; memory is not)
  float4 wt[NB], wv[NB];
  #pragma unroll
  for (int n = 0; n < NB; ++n) {
    wt[n] = make_float4(0.f, 0.f, 0.f, 0.f);
    wv[n] = make_float4(0.f, 0.f, 0.f, 0.f);
  }
  #pragma unroll
  for (int s = 0; s < NS; ++s) {
    float4 t4, vv;
    t4.x = ((code.x >> s) & 1) ? 1.f : 0.f;
    t4.y = ((code.y >> s) & 1) ? 1.f : 0.f;
    t4.z = ((code.z >> s) & 1) ? 1.f : 0.f;
    t4.w = ((code.w >> s) & 1) ? 1.f : 0.f;
    vv.x = ((code.x >> (NS + s)) & 1) ? 1.f : 0.f;
    vv.y = ((code.y >> (NS + s)) & 1) ? 1.f : 0.f;
    vv.z = ((code.z >> (NS + s)) & 1) ? 1.f : 0.f;
    vv.w = ((code.w >> (NS + s)) & 1) ? 1.f : 0.f;
    #pragma unroll
    for (int n = 0; n < NB; ++n) {
      fma4(wt[n], aw[s][n], t4);
      fma4(wv[n], av[s][n], vv);
    }
  }

  float4 acc4 = make_float4(0.f, 0.f, 0.f, 0.f);
  #pragma unroll
  for (int n = 0; n < NB; ++n) {
    float4 p = p4[n];
    p.x = clampp(p.x); p.y = clampp(p.y); p.z = clampp(p.z); p.w = clampp(p.w);
    const float4 g  = make_float4(__log2f(p.x), __log2f(p.y),
                                  __log2f(p.z), __log2f(p.w));
    const float4 g1 = make_float4(__log2f(1.0f - p.x), __log2f(1.0f - p.y),
                                  __log2f(1.0f - p.z), __log2f(1.0f - p.w));
    float4 d2 = make_float4(0.f, 0.f, 0.f, 0.f);
    #pragma unroll
    for (int c = 0; c < C; ++c) {
      const float4 r = rp[(n * C + c) * HW4 + q];
      const float dx = r.x - tg[c].x, dy = r.y - tg[c].y;
      const float dz = r.z - tg[c].z, dw = r.w - tg[c].w;
      d2.x = fmaf(dx, dx, d2.x); d2.y = fmaf(dy, dy, d2.y);
      d2.z = fmaf(dz, dz, d2.z); d2.w = fmaf(dw, dw, d2.w);
    }
    acc4.x = fmaf(g.x, -wt[n].x, fmaf(g1.x, wt[n].x - AK[n], fmaf(d2.x, wv[n].x, acc4.x)));
    acc4.y = fmaf(g.y, -wt[n].y, fmaf(g1.y, wt[n].y - AK[n], fmaf(d2.y, wv[n].y, acc4.y)));
    acc4.z = fmaf(g.z, -wt[n].z, fmaf(g1.z, wt[n].z - AK[n], fmaf(d2.z, wv[n].z, acc4.z)));
    acc4.w = fmaf(g.w, -wt[n].w, fmaf(g1.w, wt[n].w - AK[n], fmaf(d2.w, wv[n].w, acc4.w)));
  }

  float acc = (acc4.x + acc4.y) + (acc4.z + acc4.w);

  #pragma unroll
  for (int off = 32; off > 0; off >>= 1)
    acc += __shfl_down(acc, off, 64);

  __shared__ float wsum[TPB / 64];
  const int lane = threadIdx.x & 63;
  const int wid = threadIdx.x >> 6;
  if (lane == 0) wsum[wid] = acc;
  __syncthreads();
  if (threadIdx.x == 0) {
    float s = 0.f;
    #pragma unroll
    for (int i = 0; i < TPB / 64; ++i) s += wsum[i];
    constexpr float SCALE = 20.0f / (float)(B * FM1 * NB * NS);
    atomicAdd(out, s * SCALE);
  }
}

extern "C" void kernel_launch(void* const* d_in, const int* in_sizes, int n_in,
                              void* d_out, int out_size, void* d_ws, size_t ws_size,
                              hipStream_t stream) {
  const float* seg   = (const float*)d_in[0];
  const float* masks = (const float*)d_in[1];
  const float* recon = (const float*)d_in[2];
  const float* rtgt  = (const float*)d_in[3];
  const float* vis   = (const float*)d_in[4];
  const float* attn  = (const float*)d_in[5];

  float* out = (float*)d_out;
  ushort* bm = (ushort*)d_ws;  // PAIRS*HW*2B = 2.95 MB scratch

  hipMemsetAsync(out, 0, sizeof(float), stream);

  const int grid = PAIRS * BPP;  // 1440 blocks
  pack_bits<<<grid, TPB, 0, stream>>>(masks, vis, bm);
  em_rec_loss_kernel<<<grid, TPB, 0, stream>>>(seg, recon, rtgt, bm, attn, out);
}

// Round 5
// 260.226 us; speedup vs baseline: 1.0666x; 1.0666x over previous
//
#include <hip/hip_runtime.h>

#define TPB 64

namespace {
constexpr int B = 8, F = 6, NB = 5, NS = 7, H = 192, W = 192, C = 3;
constexpr int FM1 = F - 1;                 // frames 1..5
constexpr int HW = H * W;                  // 36864
constexpr int HW4 = HW / 4;                // 9216 float4 per plane
constexpr int PAIRS = B * FM1;             // 40
constexpr int BPP = HW4 / TPB;             // 144 blocks per pair
constexpr int NSLOT = 64;                  // partial-sum slots, one line each
constexpr int SLOT_STRIDE = 16;            // floats; 64 B apart
constexpr float EPS = 1e-7f;
constexpr float LN2 = 0.69314718055994530942f;
constexpr float K_BCE = LN2 / (float)HW;
constexpr float COEF = 0.1f / (float)C;
}

__device__ __forceinline__ void fma4(float4& acc, float s, const float4& v) {
  acc.x = fmaf(s, v.x, acc.x); acc.y = fmaf(s, v.y, acc.y);
  acc.z = fmaf(s, v.z, acc.z); acc.w = fmaf(s, v.w, acc.w);
}
__device__ __forceinline__ float clampp(float p) {
  return __builtin_amdgcn_fmed3f(p, EPS, 1.0f - EPS);  // v_med3_f32
}
__device__ __forceinline__ float4 step05(float4 v) {
  return make_float4(v.x > 0.5f ? 1.f : 0.f, v.y > 0.5f ? 1.f : 0.f,
                     v.z > 0.5f ? 1.f : 0.f, v.w > 0.5f ? 1.f : 0.f);
}

// Single-wave blocks (TPB=64): grid 5760 > 16-WG/CU residency cap, so the CP
// continuously refills CUs as waves retire -> sustained miss pressure instead
// of one burst + long drain. No LDS, no __syncthreads.
__global__ __launch_bounds__(TPB, 4) void em_rec_loss_kernel(
    const float* __restrict__ seg,    // [B,F,NB,H,W]
    const float* __restrict__ masks,  // [B,F,NS,H,W]
    const float* __restrict__ recon,  // [B,F,NB,C,H,W]
    const float* __restrict__ rtgt,   // [B,F,C,H,W]
    const float* __restrict__ vis,    // [B,F,NS,H,W]
    const float* __restrict__ attn,   // [B,F,NS,NB]
    float* __restrict__ partial)      // [NSLOT * SLOT_STRIDE] in d_ws
{
  const int blk = blockIdx.x;
  const int pair = blk / BPP;
  const int chunk = blk - pair * BPP;
  const int b = pair / FM1;
  const int f = pair - b * FM1 + 1;
  const int bf = b * F + f;

  // block-uniform pre-scaled attn weights (scalarized)
  float aw[NS][NB], av[NS][NB];
  const float* at = attn + (size_t)bf * NS * NB;
  #pragma unroll
  for (int s = 0; s < NS; ++s)
    #pragma unroll
    for (int n = 0; n < NB; ++n) {
      const float a = at[s * NB + n];
      aw[s][n] = a * K_BCE;
      av[s][n] = a * COEF;
    }
  float AK[NB];
  #pragma unroll
  for (int n = 0; n < NB; ++n) {
    float t = 0.f;
    #pragma unroll
    for (int s = 0; s < NS; ++s) t += aw[s][n];
    AK[n] = t;
  }

  const float4* sp = (const float4*)(seg   + (size_t)bf * NB * HW);
  const float4* mp = (const float4*)(masks + (size_t)bf * NS * HW);
  const float4* vp = (const float4*)(vis   + (size_t)bf * NS * HW);
  const float4* rp = (const float4*)(recon + (size_t)bf * NB * C * HW);
  const float4* tp = (const float4*)(rtgt  + (size_t)bf * C * HW);

  const int q = chunk * TPB + threadIdx.x;  // float4 index (4 contiguous px)

  // all 37 independent dwordx4 loads up front
  float4 m4[NS], v4[NS];
  #pragma unroll
  for (int s = 0; s < NS; ++s) m4[s] = mp[s * HW4 + q];
  #pragma unroll
  for (int s = 0; s < NS; ++s) v4[s] = vp[s * HW4 + q];
  float4 tg[C];
  #pragma unroll
  for (int c = 0; c < C; ++c) tg[c] = tp[c * HW4 + q];
  float4 p4[NB];
  #pragma unroll
  for (int n = 0; n < NB; ++n) p4[n] = sp[n * HW4 + q];

  float4 wt[NB], wv[NB];
  #pragma unroll
  for (int n = 0; n < NB; ++n) {
    wt[n] = make_float4(0.f, 0.f, 0.f, 0.f);
    wv[n] = make_float4(0.f, 0.f, 0.f, 0.f);
  }
  #pragma unroll
  for (int s = 0; s < NS; ++s) {
    const float4 t4 = step05(m4[s]);
    const float4 vv = step05(v4[s]);
    #pragma unroll
    for (int n = 0; n < NB; ++n) {
      fma4(wt[n], aw[s][n], t4);
      fma4(wv[n], av[s][n], vv);
    }
  }

  float4 acc4 = make_float4(0.f, 0.f, 0.f, 0.f);
  #pragma unroll
  for (int n = 0; n < NB; ++n) {
    float4 p = p4[n];
    p.x = clampp(p.x); p.y = clampp(p.y); p.z = clampp(p.z); p.w = clampp(p.w);
    const float4 g  = make_float4(__log2f(p.x), __log2f(p.y),
                                  __log2f(p.z), __log2f(p.w));
    const float4 g1 = make_float4(__log2f(1.0f - p.x), __log2f(1.0f - p.y),
                                  __log2f(1.0f - p.z), __log2f(1.0f - p.w));
    float4 d2 = make_float4(0.f, 0.f, 0.f, 0.f);
    #pragma unroll
    for (int c = 0; c < C; ++c) {
      const float4 r = rp[(n * C + c) * HW4 + q];
      const float dx = r.x - tg[c].x, dy = r.y - tg[c].y;
      const float dz = r.z - tg[c].z, dw = r.w - tg[c].w;
      d2.x = fmaf(dx, dx, d2.x); d2.y = fmaf(dy, dy, d2.y);
      d2.z = fmaf(dz, dz, d2.z); d2.w = fmaf(dw, dw, d2.w);
    }
    acc4.x = fmaf(g.x, -wt[n].x, fmaf(g1.x, wt[n].x - AK[n], fmaf(d2.x, wv[n].x, acc4.x)));
    acc4.y = fmaf(g.y, -wt[n].y, fmaf(g1.y, wt[n].y - AK[n], fmaf(d2.y, wv[n].y, acc4.y)));
    acc4.z = fmaf(g.z, -wt[n].z, fmaf(g1.z, wt[n].z - AK[n], fmaf(d2.z, wv[n].z, acc4.z)));
    acc4.w = fmaf(g.w, -wt[n].w, fmaf(g1.w, wt[n].w - AK[n], fmaf(d2.w, wv[n].w, acc4.w)));
  }

  float acc = (acc4.x + acc4.y) + (acc4.z + acc4.w);

  // single-wave block: pure shuffle reduce, no LDS/barrier
  #pragma unroll
  for (int off = 32; off > 0; off >>= 1)
    acc += __shfl_down(acc, off, 64);

  if (threadIdx.x == 0) {
    // spread same-line atomic pressure over 64 cache lines (~90 adds/line)
    atomicAdd(&partial[(blk & (NSLOT - 1)) * SLOT_STRIDE], acc);
  }
}

__global__ __launch_bounds__(64) void final_reduce(
    const float* __restrict__ partial, float* __restrict__ out)
{
  float v = partial[threadIdx.x * SLOT_STRIDE];
  #pragma unroll
  for (int off = 32; off > 0; off >>= 1)
    v += __shfl_down(v, off, 64);
  if (threadIdx.x == 0) {
    constexpr float SCALE = 20.0f / (float)(B * FM1 * NB * NS);
    out[0] = v * SCALE;
  }
}

extern "C" void kernel_launch(void* const* d_in, const int* in_sizes, int n_in,
                              void* d_out, int out_size, void* d_ws, size_t ws_size,
                              hipStream_t stream) {
  const float* seg   = (const float*)d_in[0];
  const float* masks = (const float*)d_in[1];
  const float* recon = (const float*)d_in[2];
  const float* rtgt  = (const float*)d_in[3];
  const float* vis   = (const float*)d_in[4];
  const float* attn  = (const float*)d_in[5];

  float* out = (float*)d_out;
  float* partial = (float*)d_ws;  // 64 slots x 64 B = 4 KB (ws is re-poisoned)

  hipMemsetAsync(partial, 0, NSLOT * SLOT_STRIDE * sizeof(float), stream);

  const int grid = PAIRS * BPP;  // 5760 single-wave blocks
  em_rec_loss_kernel<<<grid, TPB, 0, stream>>>(seg, masks, recon, rtgt, vis,
                                               attn, partial);
  final_reduce<<<1, 64, 0, stream>>>(partial, out);
}

// Round 6
// 259.152 us; speedup vs baseline: 1.0710x; 1.0041x over previous
//
#include <hip/hip_runtime.h>

#define TPB 256

namespace {
constexpr int B = 8, F = 6, NB = 5, NS = 7, H = 192, W = 192, C = 3;
constexpr int FM1 = F - 1;                 // frames 1..5
constexpr int HW = H * W;                  // 36864
constexpr int HW4 = HW / 4;                // 9216 float4 per plane
constexpr int PAIRS = B * FM1;             // 40
constexpr int BPP = HW4 / TPB;             // 36 blocks per pair
constexpr int NSLOT = 64;                  // partial-sum cache lines
constexpr int SLOT_STRIDE = 16;            // floats; 64 B apart
constexpr float EPS = 1e-7f;
constexpr float LN2 = 0.69314718055994530942f;
constexpr float K_BCE = LN2 / (float)HW;
constexpr float COEF = 0.1f / (float)C;
}

__device__ __forceinline__ void fma4(float4& acc, float s, const float4& v) {
  acc.x = fmaf(s, v.x, acc.x); acc.y = fmaf(s, v.y, acc.y);
  acc.z = fmaf(s, v.z, acc.z); acc.w = fmaf(s, v.w, acc.w);
}
__device__ __forceinline__ float clampp(float p) {
  return __builtin_amdgcn_fmed3f(p, EPS, 1.0f - EPS);  // v_med3_f32
}
__device__ __forceinline__ float4 step05(float4 v) {
  return make_float4(v.x > 0.5f ? 1.f : 0.f, v.y > 0.5f ? 1.f : 0.f,
                     v.z > 0.5f ? 1.f : 0.f, v.w > 0.5f ? 1.f : 0.f);
}

// Single-trip MLP probe: issue ALL 37 dwordx4 loads before consuming anything
// (sched_barrier(0) pins the boundary). ~190 VGPR -> 2 waves/SIMD, but each
// wave has its entire 37 KB in flight in one round trip instead of 4-5
// register-recycled batches.
__global__ __launch_bounds__(TPB, 2) void em_rec_loss_kernel(
    const float* __restrict__ seg,    // [B,F,NB,H,W]
    const float* __restrict__ masks,  // [B,F,NS,H,W]
    const float* __restrict__ recon,  // [B,F,NB,C,H,W]
    const float* __restrict__ rtgt,   // [B,F,C,H,W]
    const float* __restrict__ vis,    // [B,F,NS,H,W]
    const float* __restrict__ attn,   // [B,F,NS,NB]
    float* __restrict__ partial)      // [NSLOT * SLOT_STRIDE] in d_ws
{
  const int blk = blockIdx.x;
  const int pair = blk / BPP;
  const int chunk = blk - pair * BPP;
  const int b = pair / FM1;
  const int f = pair - b * FM1 + 1;
  const int bf = b * F + f;

  const float4* sp = (const float4*)(seg   + (size_t)bf * NB * HW);
  const float4* mp = (const float4*)(masks + (size_t)bf * NS * HW);
  const float4* vp = (const float4*)(vis   + (size_t)bf * NS * HW);
  const float4* rp = (const float4*)(recon + (size_t)bf * NB * C * HW);
  const float4* tp = (const float4*)(rtgt  + (size_t)bf * C * HW);

  const int q = chunk * TPB + threadIdx.x;  // float4 index (4 contiguous px)

  // ---------------- load region: all 37 vector loads, no consumption -------
  float4 m4[NS], v4[NS], tg[C], p4[NB], r4[NB][C];
  #pragma unroll
  for (int s = 0; s < NS; ++s) m4[s] = mp[s * HW4 + q];
  #pragma unroll
  for (int s = 0; s < NS; ++s) v4[s] = vp[s * HW4 + q];
  #pragma unroll
  for (int c = 0; c < C; ++c) tg[c] = tp[c * HW4 + q];
  #pragma unroll
  for (int n = 0; n < NB; ++n) p4[n] = sp[n * HW4 + q];
  #pragma unroll
  for (int n = 0; n < NB; ++n)
    #pragma unroll
    for (int c = 0; c < C; ++c) r4[n][c] = rp[(n * C + c) * HW4 + q];

  // block-uniform raw attn weights (in the global-load latency shadow)
  float a[NS][NB];
  const float* at = attn + (size_t)bf * NS * NB;
  #pragma unroll
  for (int s = 0; s < NS; ++s)
    #pragma unroll
    for (int n = 0; n < NB; ++n) a[s][n] = at[s * NB + n];
  float A[NB];
  #pragma unroll
  for (int n = 0; n < NB; ++n) {
    float t = 0.f;
    #pragma unroll
    for (int s = 0; s < NS; ++s) t += a[s][n];
    A[n] = t;
  }

  __builtin_amdgcn_sched_barrier(0);  // nothing below may move above

  // ---------------- compute region (consume in load order) -----------------
  float4 wt[NB], wv[NB];  // raw-weighted: wt=sum a*t, wv=sum a*vis
  #pragma unroll
  for (int n = 0; n < NB; ++n) {
    wt[n] = make_float4(0.f, 0.f, 0.f, 0.f);
    wv[n] = make_float4(0.f, 0.f, 0.f, 0.f);
  }
  #pragma unroll
  for (int s = 0; s < NS; ++s) {
    const float4 t4 = step05(m4[s]);
    const float4 vv = step05(v4[s]);
    #pragma unroll
    for (int n = 0; n < NB; ++n) {
      fma4(wt[n], a[s][n], t4);
      fma4(wv[n], a[s][n], vv);
    }
  }

  float4 accB = make_float4(0.f, 0.f, 0.f, 0.f);  // BCE (raw), scale K_BCE
  float4 accM = make_float4(0.f, 0.f, 0.f, 0.f);  // MSE (raw), scale COEF
  #pragma unroll
  for (int n = 0; n < NB; ++n) {
    float4 p = p4[n];
    p.x = clampp(p.x); p.y = clampp(p.y); p.z = clampp(p.z); p.w = clampp(p.w);
    const float4 g  = make_float4(__log2f(p.x), __log2f(p.y),
                                  __log2f(p.z), __log2f(p.w));
    const float4 g1 = make_float4(__log2f(1.0f - p.x), __log2f(1.0f - p.y),
                                  __log2f(1.0f - p.z), __log2f(1.0f - p.w));
    float4 d2 = make_float4(0.f, 0.f, 0.f, 0.f);
    #pragma unroll
    for (int c = 0; c < C; ++c) {
      const float dx = r4[n][c].x - tg[c].x, dy = r4[n][c].y - tg[c].y;
      const float dz = r4[n][c].z - tg[c].z, dw = r4[n][c].w - tg[c].w;
      d2.x = fmaf(dx, dx, d2.x); d2.y = fmaf(dy, dy, d2.y);
      d2.z = fmaf(dz, dz, d2.z); d2.w = fmaf(dw, dw, d2.w);
    }
    // BCE: g*(-wt) + g1*(wt - A)   (raw weights)
    accB.x = fmaf(g.x, -wt[n].x, fmaf(g1.x, wt[n].x - A[n], accB.x));
    accB.y = fmaf(g.y, -wt[n].y, fmaf(g1.y, wt[n].y - A[n], accB.y));
    accB.z = fmaf(g.z, -wt[n].z, fmaf(g1.z, wt[n].z - A[n], accB.z));
    accB.w = fmaf(g.w, -wt[n].w, fmaf(g1.w, wt[n].w - A[n], accB.w));
    accM.x = fmaf(d2.x, wv[n].x, accM.x);
    accM.y = fmaf(d2.y, wv[n].y, accM.y);
    accM.z = fmaf(d2.z, wv[n].z, accM.z);
    accM.w = fmaf(d2.w, wv[n].w, accM.w);
  }

  const float sB = (accB.x + accB.y) + (accB.z + accB.w);
  const float sM = (accM.x + accM.y) + (accM.z + accM.w);
  float acc = fmaf(K_BCE, sB, COEF * sM);

  #pragma unroll
  for (int off = 32; off > 0; off >>= 1)
    acc += __shfl_down(acc, off, 64);

  __shared__ float wsum[TPB / 64];
  const int lane = threadIdx.x & 63;
  const int wid = threadIdx.x >> 6;
  if (lane == 0) wsum[wid] = acc;
  __syncthreads();
  if (threadIdx.x == 0) {
    float s = 0.f;
    #pragma unroll
    for (int i = 0; i < TPB / 64; ++i) s += wsum[i];
    atomicAdd(&partial[(blk & (NSLOT - 1)) * SLOT_STRIDE], s);
  }
}

__global__ __launch_bounds__(64) void final_reduce(
    const float* __restrict__ partial, float* __restrict__ out)
{
  float v = partial[threadIdx.x * SLOT_STRIDE];
  #pragma unroll
  for (int off = 32; off > 0; off >>= 1)
    v += __shfl_down(v, off, 64);
  if (threadIdx.x == 0) {
    constexpr float SCALE = 20.0f / (float)(B * FM1 * NB * NS);
    out[0] = v * SCALE;
  }
}

extern "C" void kernel_launch(void* const* d_in, const int* in_sizes, int n_in,
                              void* d_out, int out_size, void* d_ws, size_t ws_size,
                              hipStream_t stream) {
  const float* seg   = (const float*)d_in[0];
  const float* masks = (const float*)d_in[1];
  const float* recon = (const float*)d_in[2];
  const float* rtgt  = (const float*)d_in[3];
  const float* vis   = (const float*)d_in[4];
  const float* attn  = (const float*)d_in[5];

  float* out = (float*)d_out;
  float* partial = (float*)d_ws;  // 4 KB of workspace

  hipMemsetAsync(partial, 0, NSLOT * SLOT_STRIDE * sizeof(float), stream);

  const int grid = PAIRS * BPP;  // 1440 blocks
  em_rec_loss_kernel<<<grid, TPB, 0, stream>>>(seg, masks, recon, rtgt, vis,
                                               attn, partial);
  final_reduce<<<1, 64, 0, stream>>>(partial, out);
}

// Round 7
// 238.506 us; speedup vs baseline: 1.1637x; 1.0866x over previous
//
#include <hip/hip_runtime.h>

#define TPB 256

namespace {
constexpr int B = 8, F = 6, NB = 5, NS = 7, H = 192, W = 192, C = 3;
constexpr int FM1 = F - 1;                 // frames 1..5
constexpr int HW = H * W;                  // 36864
constexpr int HW4 = HW / 4;                // 9216 float4 per plane
constexpr int PAIRS = B * FM1;             // 40
constexpr int BPP = HW4 / TPB;             // 36 blocks per pair
constexpr int NSLOT = 64;
constexpr int SLOT_STRIDE = 16;            // 64 B apart
constexpr float EPS = 1e-7f;
constexpr float LN2 = 0.69314718055994530942f;
constexpr float K_BCE = LN2 / (float)HW;
constexpr float COEF = 0.1f / (float)C;
}

typedef float v4f __attribute__((ext_vector_type(4)));

// Non-temporal 16B load: bypass/minimize L1 allocation. All 37 streams and
// all chunk strides are 0x1000/0x24000-aligned -> identical L1 set bits
// [11:6]; the whole kernel funnels through 16 of 64 L1 sets. nt takes the
// L1 fill path out of the loop.
__device__ __forceinline__ v4f ntload(const v4f* p) {
  return __builtin_nontemporal_load(p);
}

__device__ __forceinline__ v4f step05(v4f v) {
  v4f r;
  r.x = v.x > 0.5f ? 1.f : 0.f; r.y = v.y > 0.5f ? 1.f : 0.f;
  r.z = v.z > 0.5f ? 1.f : 0.f; r.w = v.w > 0.5f ? 1.f : 0.f;
  return r;
}
__device__ __forceinline__ v4f clamp4(v4f p) {
  v4f r;
  r.x = __builtin_amdgcn_fmed3f(p.x, EPS, 1.0f - EPS);
  r.y = __builtin_amdgcn_fmed3f(p.y, EPS, 1.0f - EPS);
  r.z = __builtin_amdgcn_fmed3f(p.z, EPS, 1.0f - EPS);
  r.w = __builtin_amdgcn_fmed3f(p.w, EPS, 1.0f - EPS);
  return r;
}
__device__ __forceinline__ v4f log2_4(v4f p) {
  v4f r;
  r.x = __log2f(p.x); r.y = __log2f(p.y);
  r.z = __log2f(p.z); r.w = __log2f(p.w);
  return r;
}

__global__ __launch_bounds__(TPB) void em_rec_loss_kernel(
    const float* __restrict__ seg,    // [B,F,NB,H,W]
    const float* __restrict__ masks,  // [B,F,NS,H,W]
    const float* __restrict__ recon,  // [B,F,NB,C,H,W]
    const float* __restrict__ rtgt,   // [B,F,C,H,W]
    const float* __restrict__ vis,    // [B,F,NS,H,W]
    const float* __restrict__ attn,   // [B,F,NS,NB]
    float* __restrict__ partial)
{
  const int blk = blockIdx.x;
  const int pair = blk / BPP;
  const int chunk = blk - pair * BPP;
  const int b = pair / FM1;
  const int f = pair - b * FM1 + 1;
  const int bf = b * F + f;

  // block-uniform raw attn weights (tiny, reused -> normal cached loads)
  float a[NS][NB];
  const float* at = attn + (size_t)bf * NS * NB;
  #pragma unroll
  for (int s = 0; s < NS; ++s)
    #pragma unroll
    for (int n = 0; n < NB; ++n) a[s][n] = at[s * NB + n];
  float A[NB];
  #pragma unroll
  for (int n = 0; n < NB; ++n) {
    float t = 0.f;
    #pragma unroll
    for (int s = 0; s < NS; ++s) t += a[s][n];
    A[n] = t;
  }

  const v4f* sp = (const v4f*)(seg   + (size_t)bf * NB * HW);
  const v4f* mp = (const v4f*)(masks + (size_t)bf * NS * HW);
  const v4f* vp = (const v4f*)(vis   + (size_t)bf * NS * HW);
  const v4f* rp = (const v4f*)(recon + (size_t)bf * NB * C * HW);
  const v4f* tp = (const v4f*)(rtgt  + (size_t)bf * C * HW);

  const int q = chunk * TPB + threadIdx.x;

  // masks/vis -> weighted sums
  v4f m4[NS], v4[NS];
  #pragma unroll
  for (int s = 0; s < NS; ++s) m4[s] = ntload(&mp[s * HW4 + q]);
  #pragma unroll
  for (int s = 0; s < NS; ++s) v4[s] = ntload(&vp[s * HW4 + q]);

  v4f wt[NB], wv[NB];
  #pragma unroll
  for (int n = 0; n < NB; ++n) { wt[n] = 0.f; wv[n] = 0.f; }
  #pragma unroll
  for (int s = 0; s < NS; ++s) {
    const v4f t4 = step05(m4[s]);
    const v4f vv = step05(v4[s]);
    #pragma unroll
    for (int n = 0; n < NB; ++n) {
      wt[n] += a[s][n] * t4;
      wv[n] += a[s][n] * vv;
    }
  }

  v4f tg[C];
  #pragma unroll
  for (int c = 0; c < C; ++c) tg[c] = ntload(&tp[c * HW4 + q]);

  v4f accB = 0.f, accM = 0.f;  // raw BCE / raw MSE accumulators
  #pragma unroll
  for (int n = 0; n < NB; ++n) {
    const v4f p  = clamp4(ntload(&sp[n * HW4 + q]));
    const v4f g  = log2_4(p);
    const v4f g1 = log2_4(1.0f - p);
    v4f d2 = 0.f;
    #pragma unroll
    for (int c = 0; c < C; ++c) {
      const v4f d = ntload(&rp[(n * C + c) * HW4 + q]) - tg[c];
      d2 += d * d;
    }
    accB += g1 * (wt[n] - A[n]) - g * wt[n];
    accM += d2 * wv[n];
  }

  const float sB = (accB.x + accB.y) + (accB.z + accB.w);
  const float sM = (accM.x + accM.y) + (accM.z + accM.w);
  float acc = fmaf(K_BCE, sB, COEF * sM);

  #pragma unroll
  for (int off = 32; off > 0; off >>= 1)
    acc += __shfl_down(acc, off, 64);

  __shared__ float wsum[TPB / 64];
  const int lane = threadIdx.x & 63;
  const int wid = threadIdx.x >> 6;
  if (lane == 0) wsum[wid] = acc;
  __syncthreads();
  if (threadIdx.x == 0) {
    float s = 0.f;
    #pragma unroll
    for (int i = 0; i < TPB / 64; ++i) s += wsum[i];
    atomicAdd(&partial[(blk & (NSLOT - 1)) * SLOT_STRIDE], s);
  }
}

__global__ __launch_bounds__(64) void final_reduce(
    const float* __restrict__ partial, float* __restrict__ out)
{
  float v = partial[threadIdx.x * SLOT_STRIDE];
  #pragma unroll
  for (int off = 32; off > 0; off >>= 1)
    v += __shfl_down(v, off, 64);
  if (threadIdx.x == 0) {
    constexpr float SCALE = 20.0f / (float)(B * FM1 * NB * NS);
    out[0] = v * SCALE;
  }
}

extern "C" void kernel_launch(void* const* d_in, const int* in_sizes, int n_in,
                              void* d_out, int out_size, void* d_ws, size_t ws_size,
                              hipStream_t stream) {
  const float* seg   = (const float*)d_in[0];
  const float* masks = (const float*)d_in[1];
  const float* recon = (const float*)d_in[2];
  const float* rtgt  = (const float*)d_in[3];
  const float* vis   = (const float*)d_in[4];
  const float* attn  = (const float*)d_in[5];

  float* out = (float*)d_out;
  float* partial = (float*)d_ws;

  hipMemsetAsync(partial, 0, NSLOT * SLOT_STRIDE * sizeof(float), stream);

  const int grid = PAIRS * BPP;  // 1440 blocks
  em_rec_loss_kernel<<<grid, TPB, 0, stream>>>(seg, masks, recon, rtgt, vis,
                                               attn, partial);
  final_reduce<<<1, 64, 0, stream>>>(partial, out);
}

// Round 8
// 237.557 us; speedup vs baseline: 1.1684x; 1.0040x over previous
//
#include <hip/hip_runtime.h>

#define TPB 256

namespace {
constexpr int B = 8, F = 6, NB = 5, NS = 7, H = 192, W = 192, C = 3;
constexpr int FM1 = F - 1;                 // frames 1..5
constexpr int HW = H * W;                  // 36864
constexpr int HW4 = HW / 4;                // 9216 float4 per plane
constexpr int PAIRS = B * FM1;             // 40
constexpr int BPP = HW4 / TPB;             // 36 blocks per pair
constexpr int NSLOT = 64;
constexpr int SLOT_STRIDE = 16;            // 64 B apart
constexpr float EPS = 1e-7f;
constexpr float LN2 = 0.69314718055994530942f;
constexpr float K_BCE = LN2 / (float)HW;
constexpr float COEF = 0.1f / (float)C;
}

typedef float v4f __attribute__((ext_vector_type(4)));

__device__ __forceinline__ v4f ntload(const v4f* p) {
  return __builtin_nontemporal_load(p);   // single-use data: skip L1 alloc
}
__device__ __forceinline__ v4f step05(v4f v) {
  v4f r;
  r.x = v.x > 0.5f ? 1.f : 0.f; r.y = v.y > 0.5f ? 1.f : 0.f;
  r.z = v.z > 0.5f ? 1.f : 0.f; r.w = v.w > 0.5f ? 1.f : 0.f;
  return r;
}
__device__ __forceinline__ v4f clamp4(v4f p) {
  v4f r;
  r.x = __builtin_amdgcn_fmed3f(p.x, EPS, 1.0f - EPS);
  r.y = __builtin_amdgcn_fmed3f(p.y, EPS, 1.0f - EPS);
  r.z = __builtin_amdgcn_fmed3f(p.z, EPS, 1.0f - EPS);
  r.w = __builtin_amdgcn_fmed3f(p.w, EPS, 1.0f - EPS);
  return r;
}
__device__ __forceinline__ v4f log2_4(v4f p) {
  v4f r;
  r.x = __log2f(p.x); r.y = __log2f(p.y);
  r.z = __log2f(p.z); r.w = __log2f(p.w);
  return r;
}

__global__ __launch_bounds__(TPB) void em_rec_loss_kernel(
    const float* __restrict__ seg,    // [B,F,NB,H,W]
    const float* __restrict__ masks,  // [B,F,NS,H,W]
    const float* __restrict__ recon,  // [B,F,NB,C,H,W]
    const float* __restrict__ rtgt,   // [B,F,C,H,W]
    const float* __restrict__ vis,    // [B,F,NS,H,W]
    const float* __restrict__ attn,   // [B,F,NS,NB]
    float* __restrict__ partial)
{
  const int blk = blockIdx.x;
  const int pair = blk / BPP;
  const int chunk = blk - pair * BPP;
  const int b = pair / FM1;
  const int f = pair - b * FM1 + 1;
  const int bf = b * F + f;

  // block-uniform raw attn weights
  float a[NS][NB];
  const float* at = attn + (size_t)bf * NS * NB;
  #pragma unroll
  for (int s = 0; s < NS; ++s)
    #pragma unroll
    for (int n = 0; n < NB; ++n) a[s][n] = at[s * NB + n];
  float A[NB];
  #pragma unroll
  for (int n = 0; n < NB; ++n) {
    float t = 0.f;
    #pragma unroll
    for (int s = 0; s < NS; ++s) t += a[s][n];
    A[n] = t;
  }

  const v4f* sp = (const v4f*)(seg   + (size_t)bf * NB * HW);
  const v4f* mp = (const v4f*)(masks + (size_t)bf * NS * HW);
  const v4f* vp = (const v4f*)(vis   + (size_t)bf * NS * HW);
  const v4f* rp = (const v4f*)(recon + (size_t)bf * NB * C * HW);
  const v4f* tp = (const v4f*)(rtgt  + (size_t)bf * C * HW);

  // Per-pair phase rotation: every plane/chunk stride is a 4 KB multiple, so
  // without rotation ALL loads machine-wide share address bits [11:4] ->
  // instantaneous channel/L3-slice imbalance. rot = pair*231 float4s
  // (3696 B, not 4K-congruent) gives 40 distinct phases. Bijective on the
  // pair's pixels, so the sum is unchanged; coalescing intact except the
  // one seam wave per pair.
  const int rot = pair * 231;
  int q = chunk * TPB + threadIdx.x + rot;
  if (q >= HW4) q -= HW4;

  v4f m4[NS], v4[NS];
  #pragma unroll
  for (int s = 0; s < NS; ++s) m4[s] = ntload(&mp[s * HW4 + q]);
  #pragma unroll
  for (int s = 0; s < NS; ++s) v4[s] = ntload(&vp[s * HW4 + q]);

  v4f wt[NB], wv[NB];
  #pragma unroll
  for (int n = 0; n < NB; ++n) { wt[n] = 0.f; wv[n] = 0.f; }
  #pragma unroll
  for (int s = 0; s < NS; ++s) {
    const v4f t4 = step05(m4[s]);
    const v4f vv = step05(v4[s]);
    #pragma unroll
    for (int n = 0; n < NB; ++n) {
      wt[n] += a[s][n] * t4;
      wv[n] += a[s][n] * vv;
    }
  }

  v4f tg[C];
  #pragma unroll
  for (int c = 0; c < C; ++c) tg[c] = ntload(&tp[c * HW4 + q]);

  v4f accB = 0.f, accM = 0.f;
  #pragma unroll
  for (int n = 0; n < NB; ++n) {
    const v4f p  = clamp4(ntload(&sp[n * HW4 + q]));
    const v4f g  = log2_4(p);
    const v4f g1 = log2_4(1.0f - p);
    v4f d2 = 0.f;
    #pragma unroll
    for (int c = 0; c < C; ++c) {
      const v4f d = ntload(&rp[(n * C + c) * HW4 + q]) - tg[c];
      d2 += d * d;
    }
    accB += g1 * (wt[n] - A[n]) - g * wt[n];
    accM += d2 * wv[n];
  }

  const float sB = (accB.x + accB.y) + (accB.z + accB.w);
  const float sM = (accM.x + accM.y) + (accM.z + accM.w);
  float acc = fmaf(K_BCE, sB, COEF * sM);

  #pragma unroll
  for (int off = 32; off > 0; off >>= 1)
    acc += __shfl_down(acc, off, 64);

  __shared__ float wsum[TPB / 64];
  const int lane = threadIdx.x & 63;
  const int wid = threadIdx.x >> 6;
  if (lane == 0) wsum[wid] = acc;
  __syncthreads();
  if (threadIdx.x == 0) {
    float s = 0.f;
    #pragma unroll
    for (int i = 0; i < TPB / 64; ++i) s += wsum[i];
    atomicAdd(&partial[(blk & (NSLOT - 1)) * SLOT_STRIDE], s);
  }
}

__global__ __launch_bounds__(64) void final_reduce(
    const float* __restrict__ partial, float* __restrict__ out)
{
  float v = partial[threadIdx.x * SLOT_STRIDE];
  #pragma unroll
  for (int off = 32; off > 0; off >>= 1)
    v += __shfl_down(v, off, 64);
  if (threadIdx.x == 0) {
    constexpr float SCALE = 20.0f / (float)(B * FM1 * NB * NS);
    out[0] = v * SCALE;
  }
}

extern "C" void kernel_launch(void* const* d_in, const int* in_sizes, int n_in,
                              void* d_out, int out_size, void* d_ws, size_t ws_size,
                              hipStream_t stream) {
  const float* seg   = (const float*)d_in[0];
  const float* masks = (const float*)d_in[1];
  const float* recon = (const float*)d_in[2];
  const float* rtgt  = (const float*)d_in[3];
  const float* vis   = (const float*)d_in[4];
  const float* attn  = (const float*)d_in[5];

  float* out = (float*)d_out;
  float* partial = (float*)d_ws;

  hipMemsetAsync(partial, 0, NSLOT * SLOT_STRIDE * sizeof(float), stream);

  const int grid = PAIRS * BPP;  // 1440 blocks
  em_rec_loss_kernel<<<grid, TPB, 0, stream>>>(seg, masks, recon, rtgt, vis,
                                               attn, partial);
  final_reduce<<<1, 64, 0, stream>>>(partial, out);
}